// Round 6
// baseline (1633.505 us; speedup 1.0000x reference)
//
#include <hip/hip_runtime.h>
#include <hip/hip_bf16.h>
#include <math.h>

typedef unsigned short u16;
typedef __bf16 bf16x8_t __attribute__((ext_vector_type(8)));
typedef float  f32x4_t  __attribute__((ext_vector_type(4)));
typedef float  f32x8_t  __attribute__((ext_vector_type(8)));
typedef float  f32x16_t __attribute__((ext_vector_type(16)));
typedef u16    u16x4_t  __attribute__((ext_vector_type(4)));
typedef u16    u16x8_t  __attribute__((ext_vector_type(8)));

// ---------- helpers ----------
__device__ __forceinline__ u16 f2b(float f) {
  unsigned u = __builtin_bit_cast(unsigned, f);
  u += 0x7fffu + ((u >> 16) & 1u);      // RNE; inputs are finite
  return (u16)(u >> 16);
}
__device__ __forceinline__ float b2f(u16 h) {
  unsigned u = ((unsigned)h) << 16;
  return __builtin_bit_cast(float, u);
}
__device__ __forceinline__ float sigm_(float x) { return 1.0f / (1.0f + __expf(-x)); }
__device__ __forceinline__ float tanh_(float x) { return 1.0f - 2.0f / (__expf(2.0f * x) + 1.0f); }

__device__ __forceinline__ void gload16(const void* g, void* l) {
  __builtin_amdgcn_global_load_lds(
      (__attribute__((address_space(1))) void*)(g),
      (__attribute__((address_space(3))) void*)(l), 16, 0, 0);
}

// ==========================================================================
// Packed panel format: tiles of 256 rows x 32 k, 16 KB each, laid out as
//   [k-plane p=0..3][row 0..255][8 u16]   (plane = k sub-slice of 8)
// Panel = [row_block][k_tile][tile(8192 u16)], k-tile stride = KT per panel.
// Two consecutive panel tiles form one K64 LDS image with plane stride 2048,
// so frag addr = base + (2*ks + (lane>>5))*2048 + row*8 spans K64 seamlessly.
// ==========================================================================

// ---------- pack fp32 activations [B,C] -> packed bf16 panel (col offset c0) ----------
__global__ void cvt_act_kernel(const float* __restrict__ src, u16* __restrict__ dst,
                               int C, int KT, int c0) {
  int mb = blockIdx.x, ktl = blockIdx.y, t = threadIdx.x;
  int ktg = (c0 >> 5) + ktl;
  const float* s = src + (long)(mb * 256 + t) * C + ktl * 32;
  u16* d = dst + ((long)(mb * KT + ktg)) * 8192 + t * 8;
#pragma unroll
  for (int p = 0; p < 4; ++p) {
    f32x8_t v = *(const f32x8_t*)(s + p * 8);
    u16x8_t o;
#pragma unroll
    for (int r = 0; r < 8; ++r) o[r] = f2b(v[r]);
    *(u16x8_t*)(d + p * 2048) = o;
  }
}

// ---------- pack fp32 weight [K,N] (transposed) -> packed bf16 panel ----------
__global__ void cvt_wt_kernel(const float* __restrict__ src, u16* __restrict__ dst,
                              int N, int KT, int n0, int k0) {
  int bx = blockIdx.x, by = blockIdx.y, t = threadIdx.x;
  int n = bx * 256 + t;
  int nb_g = (n0 >> 8) + bx;
  int ktg = (k0 >> 5) + by;
  float tmp[32];
#pragma unroll
  for (int kk = 0; kk < 32; ++kk)
    tmp[kk] = src[(long)(by * 32 + kk) * N + n];
  u16* d = dst + ((long)(nb_g * KT + ktg)) * 8192 + t * 8;
#pragma unroll
  for (int p = 0; p < 4; ++p) {
    u16x8_t o;
#pragma unroll
    for (int r = 0; r < 8; ++r) o[r] = f2b(tmp[p * 8 + r]);
    *(u16x8_t*)(d + p * 2048) = o;
  }
}

// ==========================================================================
// 256x256 bf16 GEMM, 32x32x16 MFMA, register-double-buffered K16 slices.
// 8 waves (2M x 4N), per-wave output 128x64 = acc[4 m][2 n] f32x16.
// LDS: 2 bufs x (A 32KB + B 32KB) = 128 KiB. One barrier + one vmcnt per
// K64 iter; NO manual lgkmcnt -- the frag-set rotation forces the compiler
// to emit counted lgkm waits, overlapping ds_read with the MFMA clusters.
// Staging for t+1 fully issued in phases 0-1 (>=1500 cyc before vmcnt(0)).
// Operands swapped (W as A-op, X as B-op): lane's 16 acc elems = output
// row (lane&31), cols (reg&3)+8*(reg>>2)+4*(lane>>5)  [m74/m101 layout].
// MODE 0: A1p[64mb x 160kt] x W1tp[32nb x 160kt] -> G1 [16384,8192]
//         NT (K64 iters): nb<16 -> 80, nb<28 -> 48, else 32
// MODE 1: A2p[64mb x 128kt] x W2tp[8nb x 128kt]  -> G2 [16384,2048], NT=32
// ==========================================================================
template <int MODE>
__global__ __launch_bounds__(512, 2) void gemm256_kernel(
    const u16* __restrict__ A, const u16* __restrict__ Bt, u16* __restrict__ Cout) {
  constexpr int KTF  = (MODE == 0) ? 160 : 128;  // panel stride in K32 tiles
  constexpr int NCOL = (MODE == 0) ? 8192 : 2048;
  constexpr int NBN  = NCOL / 256;

  __shared__ u16 lds[2 * 32768];  // per buf: A tiles [0,16384), B tiles [16384,32768)

  // XCD-bijective swizzle (grid % 8 == 0 in both modes)
  int bid = blockIdx.x;
  int cpx = gridDim.x >> 3;
  bid = (bid & 7) * cpx + (bid >> 3);

  int mb = bid / NBN, nb = bid % NBN;
  int m0 = mb * 256, n0 = nb * 256;

  int kt0, NT;  // kt0 in K32 units, NT in K64 iters
  if (MODE == 0) { kt0 = 0; NT = (nb < 16) ? 80 : ((nb < 28) ? 48 : 32); }
  else           { kt0 = (nb < 4) ? 0 : 64; NT = 32; }

  const int tid  = threadIdx.x;
  const int lane = tid & 63;
  const int wid  = tid >> 6;
  const int wr   = wid >> 2;       // 0..1  (wave row: 128 output rows)
  const int wc   = wid & 3;        // 0..3  (wave col: 64 output cols)
  const int l31  = lane & 31;
  const int hl   = lane >> 5;

  // staging: per thread 16B slice; per iter copy 2 consecutive K32 tiles/op
  const int dstg = tid * 8;  // u16
  const u16* pA = A  + ((long)(mb * KTF + kt0)) * 8192 + dstg;
  const u16* pB = Bt + ((long)(nb * KTF + kt0)) * 8192 + dstg;

  // STG(bufb, tt, g): A half-tile g and B half-tile g (g=0..3) of iter tt
#define STG(bufb, tt, g) do { \
    gload16(pA + ((long)(2 * (tt))) * 8192 + (g) * 4096, \
            &lds[(bufb) * 32768 + (g) * 4096 + dstg]); \
    gload16(pB + ((long)(2 * (tt))) * 8192 + (g) * 4096, \
            &lds[(bufb) * 32768 + 16384 + (g) * 4096 + dstg]); } while (0)

  // fragment offsets (u16 units) within a K64 buffer image
  const int xbase = (wr * 128 + l31) * 8;  // + mm*256
  const int wbase = (wc * 64  + l31) * 8;  // + nn*256

  struct Frag { bf16x8_t x0, x1, x2, x3, w0, w1; };
  Frag fA, fB;

#define RD(F, sbp, ks) do { \
    const u16* _t = (sbp) + (2 * (ks) + hl) * 2048; \
    F.x0 = *(const bf16x8_t*)(_t + xbase); \
    F.x1 = *(const bf16x8_t*)(_t + xbase + 256); \
    F.x2 = *(const bf16x8_t*)(_t + xbase + 512); \
    F.x3 = *(const bf16x8_t*)(_t + xbase + 768); \
    F.w0 = *(const bf16x8_t*)(_t + 16384 + wbase); \
    F.w1 = *(const bf16x8_t*)(_t + 16384 + wbase + 256); } while (0)

#define MM(F) do { \
    acc[0][0] = __builtin_amdgcn_mfma_f32_32x32x16_bf16(F.w0, F.x0, acc[0][0], 0, 0, 0); \
    acc[0][1] = __builtin_amdgcn_mfma_f32_32x32x16_bf16(F.w1, F.x0, acc[0][1], 0, 0, 0); \
    acc[1][0] = __builtin_amdgcn_mfma_f32_32x32x16_bf16(F.w0, F.x1, acc[1][0], 0, 0, 0); \
    acc[1][1] = __builtin_amdgcn_mfma_f32_32x32x16_bf16(F.w1, F.x1, acc[1][1], 0, 0, 0); \
    acc[2][0] = __builtin_amdgcn_mfma_f32_32x32x16_bf16(F.w0, F.x2, acc[2][0], 0, 0, 0); \
    acc[2][1] = __builtin_amdgcn_mfma_f32_32x32x16_bf16(F.w1, F.x2, acc[2][1], 0, 0, 0); \
    acc[3][0] = __builtin_amdgcn_mfma_f32_32x32x16_bf16(F.w0, F.x3, acc[3][0], 0, 0, 0); \
    acc[3][1] = __builtin_amdgcn_mfma_f32_32x32x16_bf16(F.w1, F.x3, acc[3][1], 0, 0, 0); } while (0)

  f32x16_t acc[4][2];
#pragma unroll
  for (int m = 0; m < 4; ++m)
#pragma unroll
    for (int n = 0; n < 2; ++n)
#pragma unroll
      for (int r = 0; r < 16; ++r) acc[m][n][r] = 0.f;

  // ---- prologue: stage tile-pair 0 into buf0 ----
  STG(0, 0, 0); STG(0, 0, 1); STG(0, 0, 2); STG(0, 0, 3);
  asm volatile("s_waitcnt vmcnt(0)" ::: "memory");
  __builtin_amdgcn_s_barrier();

  for (int t = 0; t < NT; ++t) {
    const int buf = t & 1;
    const u16* sb = &lds[buf * 32768];
    const bool pre = (t + 1 < NT);

    RD(fA, sb, 0);
    // phase 0: read slice1, stage halves 0-1, MFMA slice0
    RD(fB, sb, 1);
    if (pre) { STG(buf ^ 1, t + 1, 0); STG(buf ^ 1, t + 1, 1); }
    __builtin_amdgcn_s_setprio(1); MM(fA); __builtin_amdgcn_s_setprio(0);
    // phase 1: read slice2, stage halves 2-3, MFMA slice1
    RD(fA, sb, 2);
    if (pre) { STG(buf ^ 1, t + 1, 2); STG(buf ^ 1, t + 1, 3); }
    __builtin_amdgcn_s_setprio(1); MM(fB); __builtin_amdgcn_s_setprio(0);
    // phase 2: read slice3, MFMA slice2
    RD(fB, sb, 3);
    __builtin_amdgcn_s_setprio(1); MM(fA); __builtin_amdgcn_s_setprio(0);
    // phase 3: MFMA slice3
    __builtin_amdgcn_s_setprio(1); MM(fB); __builtin_amdgcn_s_setprio(0);

    asm volatile("s_waitcnt vmcnt(0)" ::: "memory");  // next tile resident
    __builtin_amdgcn_s_barrier();
  }
#undef STG
#undef RD
#undef MM

  // ---- epilogue: out row = lane&31 (+mm*32), cols = nn*32 + g*8 + 4*hl + 0..3
  const long rowg = (long)(m0 + wr * 128 + l31);
  const int  colg = n0 + wc * 64 + 4 * hl;
#pragma unroll
  for (int mm = 0; mm < 4; ++mm) {
    long rb = (rowg + mm * 32) * (long)NCOL;
#pragma unroll
    for (int nn = 0; nn < 2; ++nn) {
#pragma unroll
      for (int g = 0; g < 4; ++g) {
        u16x4_t o;
#pragma unroll
        for (int r = 0; r < 4; ++r) o[r] = f2b(acc[mm][nn][g * 4 + r]);
        *(u16x4_t*)&Cout[rb + colg + nn * 32 + g * 8] = o;
      }
    }
  }
}

// ---------- pass2: gates -> c_new (fp32), A2 packed = [bf16(c_new) | bf16(tanh(c_new))] ----------
__global__ void pass2_kernel(const u16* __restrict__ G1, const float* __restrict__ c_t,
                             const float* __restrict__ bias_i, const float* __restrict__ bias_f,
                             const float* __restrict__ bias_c,
                             float* __restrict__ c_new_out, u16* __restrict__ A2p) {
  int mb = blockIdx.x, jg = blockIdx.y, t = threadIdx.x;
  int b = mb * 256 + t;
  int j0 = jg * 32;
  const u16* row = G1 + (long)b * 8192 + j0;
  const float* cp_p = c_t + (long)b * 2048 + j0;
  float* co_p = c_new_out + (long)b * 2048 + j0;
  u16* dc = A2p + ((long)(mb * 128 + jg)) * 8192 + t * 8;
  u16* dr = dc + (long)64 * 8192;

#pragma unroll
  for (int q = 0; q < 4; ++q) {
    u16x8_t ip = *(const u16x8_t*)(row + q * 8);
    u16x8_t fp = *(const u16x8_t*)(row + 2048 + q * 8);
    u16x8_t gp = *(const u16x8_t*)(row + 4096 + q * 8);
    f32x8_t cp = *(const f32x8_t*)(cp_p + q * 8);
    f32x8_t bi = *(const f32x8_t*)(bias_i + j0 + q * 8);
    f32x8_t bf = *(const f32x8_t*)(bias_f + j0 + q * 8);
    f32x8_t bc = *(const f32x8_t*)(bias_c + j0 + q * 8);
    f32x8_t cn;
    u16x8_t cb, rb;
#pragma unroll
    for (int r = 0; r < 8; ++r) {
      float ig = sigm_(b2f(ip[r]) + bi[r]);
      float fg = sigm_(b2f(fp[r]) + bf[r]);
      float g  = tanh_(b2f(gp[r]) + bc[r]);
      float c  = fg * cp[r] + ig * g;
      cn[r] = c;
      cb[r] = f2b(c);
      rb[r] = f2b(tanh_(c));
    }
    *(f32x8_t*)(co_p + q * 8) = cn;
    *(u16x8_t*)(dc + q * 2048) = cb;
    *(u16x8_t*)(dr + q * 2048) = rb;
  }
}

// ---------- pass3: h_new = sigmoid(og_pre + c@Woc + bias_o) * (m_t + xr) ----------
__global__ void pass3_kernel(const u16* __restrict__ G1, const u16* __restrict__ G2,
                             const float* __restrict__ bias_o, float* __restrict__ h_out) {
  long i = (long)blockIdx.x * blockDim.x + threadIdx.x;
  long e = i * 8;
  int b = (int)(e >> 10);
  int j = (int)(e & 1023);
  const u16* row1 = G1 + (long)b * 8192;
  const u16* row2 = G2 + (long)b * 2048;
  u16x8_t ogp = *(const u16x8_t*)(row1 + 6144 + j);
  u16x8_t xrp = *(const u16x8_t*)(row1 + 7168 + j);
  u16x8_t ocg = *(const u16x8_t*)(row2 + j);
  u16x8_t mt  = *(const u16x8_t*)(row2 + 1024 + j);
  f32x8_t bo  = *(const f32x8_t*)(bias_o + j);
  f32x8_t h;
#pragma unroll
  for (int r = 0; r < 8; ++r) {
    float og = sigm_(b2f(ogp[r]) + b2f(ocg[r]) + bo[r]);
    h[r] = og * (b2f(mt[r]) + b2f(xrp[r]));
  }
  *(f32x8_t*)(h_out + (long)b * 1024 + j) = h;
}

// ---------- launch ----------
extern "C" void kernel_launch(void* const* d_in, const int* in_sizes, int n_in,
                              void* d_out, int out_size, void* d_ws, size_t ws_size,
                              hipStream_t stream) {
  const float* x_t      = (const float*)d_in[0];
  const float* h_t      = (const float*)d_in[1];
  const float* c_t      = (const float*)d_in[2];
  const float* w_if_x   = (const float*)d_in[3];
  const float* w_if_h   = (const float*)d_in[4];
  const float* w_if_c   = (const float*)d_in[5];
  const float* bias_i   = (const float*)d_in[6];
  const float* bias_f   = (const float*)d_in[7];
  const float* w_c_x    = (const float*)d_in[8];
  const float* w_c_h    = (const float*)d_in[9];
  const float* bias_c   = (const float*)d_in[10];
  const float* w_o_x    = (const float*)d_in[11];
  const float* w_o_h    = (const float*)d_in[12];
  const float* w_o_c    = (const float*)d_in[13];
  const float* bias_o   = (const float*)d_in[14];
  const float* w_r_proj = (const float*)d_in[15];
  const float* w_r_x    = (const float*)d_in[16];

  char* ws = (char*)d_ws;
  u16* A1p  = (u16*)(ws);
  u16* W1tp = (u16*)(ws + 167772160L);
  u16* G1   = (u16*)(ws + 251658240L);
  u16* W2tp = (u16*)(ws + 520093696L);
  u16* A2p  = (u16*)(ws);               // aliases A1p (dead after GEMM1)
  u16* G2   = (u16*)(ws + 167772160L);  // aliases W1tp (dead after GEMM1)

  float* h_out = (float*)d_out;
  float* c_out = h_out + 16384L * 1024L;

  // --- stage 0: pack activations (A1 panel k-map: x 0..63, h 64..95, c 96..159) ---
  cvt_act_kernel<<<dim3(64, 64), 256, 0, stream>>>(x_t, A1p, 2048, 160, 0);
  cvt_act_kernel<<<dim3(64, 32), 256, 0, stream>>>(h_t, A1p, 1024, 160, 2048);
  cvt_act_kernel<<<dim3(64, 64), 256, 0, stream>>>(c_t, A1p, 2048, 160, 3072);

  // --- pack weights (transposed) ---
  cvt_wt_kernel<<<dim3(16, 64), 256, 0, stream>>>(w_if_x,   W1tp, 4096, 160, 0,    0);
  cvt_wt_kernel<<<dim3(16, 32), 256, 0, stream>>>(w_if_h,   W1tp, 4096, 160, 0,    2048);
  cvt_wt_kernel<<<dim3(16, 64), 256, 0, stream>>>(w_if_c,   W1tp, 4096, 160, 0,    3072);
  cvt_wt_kernel<<<dim3(8,  64), 256, 0, stream>>>(w_c_x,    W1tp, 2048, 160, 4096, 0);
  cvt_wt_kernel<<<dim3(8,  32), 256, 0, stream>>>(w_c_h,    W1tp, 2048, 160, 4096, 2048);
  cvt_wt_kernel<<<dim3(4,  64), 256, 0, stream>>>(w_o_x,    W1tp, 1024, 160, 6144, 0);
  cvt_wt_kernel<<<dim3(4,  32), 256, 0, stream>>>(w_o_h,    W1tp, 1024, 160, 6144, 2048);
  cvt_wt_kernel<<<dim3(4,  64), 256, 0, stream>>>(w_r_x,    W1tp, 1024, 160, 7168, 0);
  cvt_wt_kernel<<<dim3(4,  64), 256, 0, stream>>>(w_o_c,    W2tp, 1024, 128, 0,    0);
  cvt_wt_kernel<<<dim3(4,  64), 256, 0, stream>>>(w_r_proj, W2tp, 1024, 128, 1024, 2048);

  // --- stage 1: big fused GEMM -> all pre-activations ---
  gemm256_kernel<0><<<2048, 512, 0, stream>>>(A1p, W1tp, G1);

  // --- stage 2: elementwise gates -> c_new + packed A2 ---
  pass2_kernel<<<dim3(64, 64), 256, 0, stream>>>(G1, c_t, bias_i, bias_f, bias_c, c_out, A2p);

  // --- stage 3: [c_new|r_t] GEMM -> og peephole + m_t ---
  gemm256_kernel<1><<<512, 512, 0, stream>>>(A2p, W2tp, G2);

  // --- stage 4: h_new ---
  pass3_kernel<<<8192, 256, 0, stream>>>(G1, G2, bias_o, h_out);
}